// Round 1
// baseline (89.350 us; speedup 1.0000x reference)
//
#include <hip/hip_runtime.h>
#include <hip/hip_bf16.h>

#define B_DIM 16384
#define P_DIM 4096
#define D_DIM 256

typedef float f32x4 __attribute__((ext_vector_type(4)));
typedef __bf16 bf16x8 __attribute__((ext_vector_type(8)));

__device__ __forceinline__ unsigned short f2bf_rne(float f) {
  unsigned int u = __builtin_bit_cast(unsigned int, f);
  u += 0x7fffu + ((u >> 16) & 1u);
  return (unsigned short)(u >> 16);
}

// One wave per row: fp32 -> bf16 conversion + fp32 sum-of-squares.
__global__ __launch_bounds__(256) void prep_kernel(
    const float* __restrict__ x, const float* __restrict__ p,
    unsigned short* __restrict__ xb, unsigned short* __restrict__ pb,
    float* __restrict__ xsq, float* __restrict__ psq) {
  int row  = blockIdx.x * 4 + (threadIdx.x >> 6);
  int lane = threadIdx.x & 63;
  const float4* src;
  unsigned short* dst;
  float* sq;
  if (row < B_DIM) {
    src = (const float4*)(x + (size_t)row * D_DIM);
    dst = xb + (size_t)row * D_DIM;
    sq  = xsq + row;
  } else {
    int r = row - B_DIM;
    src = (const float4*)(p + (size_t)r * D_DIM);
    dst = pb + (size_t)r * D_DIM;
    sq  = psq + r;
  }
  float4 v = src[lane];
  ushort4 o;
  o.x = f2bf_rne(v.x); o.y = f2bf_rne(v.y);
  o.z = f2bf_rne(v.z); o.w = f2bf_rne(v.w);
  ((ushort4*)dst)[lane] = o;
  float s = v.x * v.x + v.y * v.y + v.z * v.z + v.w * v.w;
  #pragma unroll
  for (int off = 32; off > 0; off >>= 1) s += __shfl_down(s, off);
  if (lane == 0) *sq = s;
}

__device__ __forceinline__ void async16(const unsigned short* g, void* l) {
  __builtin_amdgcn_global_load_lds(
      (const __attribute__((address_space(1))) void*)g,
      (__attribute__((address_space(3))) void*)l,
      16, 0, 0);
}

// 128x128 tile, BK=32, 4 waves (2x2), 16x16x32 bf16 MFMA, m97 structure.
__global__ __launch_bounds__(256, 2) void dist_gemm(
    const unsigned short* __restrict__ A,   // [B_DIM][D_DIM] bf16 bits
    const unsigned short* __restrict__ Bm,  // [P_DIM][D_DIM] bf16 bits
    const float* __restrict__ xsq, const float* __restrict__ psq,
    float* __restrict__ out) {
  __shared__ __align__(16) __bf16 As[128 * 32];
  __shared__ __align__(16) __bf16 Bs[128 * 32];

  const int tid  = threadIdx.x;
  const int w    = tid >> 6;
  const int lane = tid & 63;

  // XCD-aware bijective swizzle (4096 blocks, 8 XCDs, 4096%8==0)
  const int bid = blockIdx.x;
  const int swz = (bid & 7) * 512 + (bid >> 3);
  const int bm  = swz >> 5;  // 0..127  (rows of x)
  const int bn  = swz & 31;  // 0..31   (prototype panel)

  const int wr = w >> 1;  // 0..1
  const int wc = w & 1;   // 0..1

  f32x4 acc[4][4];
  #pragma unroll
  for (int m = 0; m < 4; ++m)
    #pragma unroll
    for (int n = 0; n < 4; ++n) acc[m][n] = 0.0f;

  // Staging: each tile is 8192 B; wave w stages bytes [w*2048, w*2048+2048)
  // via two 1024 B global_load_lds issues (16 B/lane, linear LDS dest).
  const int ofs0 = w * 2048 + lane * 16;
  const int ofs1 = ofs0 + 1024;
  const int r0 = ofs0 >> 6, c0 = (ofs0 & 63) >> 1;  // row, k-elem within tile
  const int r1 = ofs1 >> 6, c1 = (ofs1 & 63) >> 1;

  const unsigned short* a0 = A  + (size_t)(bm * 128 + r0) * D_DIM + c0;
  const unsigned short* a1 = A  + (size_t)(bm * 128 + r1) * D_DIM + c1;
  const unsigned short* b0 = Bm + (size_t)(bn * 128 + r0) * D_DIM + c0;
  const unsigned short* b1 = Bm + (size_t)(bn * 128 + r1) * D_DIM + c1;

  char* ldsA = (char*)As + w * 2048;
  char* ldsB = (char*)Bs + w * 2048;

  const int ar = wr * 64 + (lane & 15);
  const int br = wc * 64 + (lane & 15);
  const int kk = (lane >> 4) * 8;

  #pragma unroll 1
  for (int kt = 0; kt < D_DIM; kt += 32) {
    async16(a0 + kt, ldsA);
    async16(a1 + kt, ldsA + 1024);
    async16(b0 + kt, ldsB);
    async16(b1 + kt, ldsB + 1024);
    __syncthreads();

    bf16x8 av[4], bv[4];
    #pragma unroll
    for (int m = 0; m < 4; ++m)
      av[m] = *(const bf16x8*)(As + (ar + m * 16) * 32 + kk);
    #pragma unroll
    for (int n = 0; n < 4; ++n)
      bv[n] = *(const bf16x8*)(Bs + (br + n * 16) * 32 + kk);

    #pragma unroll
    for (int m = 0; m < 4; ++m)
      #pragma unroll
      for (int n = 0; n < 4; ++n)
        acc[m][n] = __builtin_amdgcn_mfma_f32_16x16x32_bf16(av[m], bv[n], acc[m][n], 0, 0, 0);
    __syncthreads();
  }

  // Epilogue: out = sqrt(max(xsq + psq - 2*xp, 0))
  // C/D layout (verified): col = lane&15, row = (lane>>4)*4 + reg
  const int row0 = bm * 128 + wr * 64 + (lane >> 4) * 4;
  const int col0 = bn * 128 + wc * 64 + (lane & 15);
  #pragma unroll
  for (int m = 0; m < 4; ++m) {
    #pragma unroll
    for (int n = 0; n < 4; ++n) {
      const int col = col0 + n * 16;
      const float ps = psq[col];
      #pragma unroll
      for (int j = 0; j < 4; ++j) {
        const int row = row0 + m * 16 + j;
        const float xs = xsq[row];
        float v = fmaf(-2.0f, acc[m][n][j], xs + ps);
        v = fmaxf(v, 0.0f);
        out[(size_t)row * P_DIM + col] = __builtin_sqrtf(v);
      }
    }
  }
}

extern "C" void kernel_launch(void* const* d_in, const int* in_sizes, int n_in,
                              void* d_out, int out_size, void* d_ws, size_t ws_size,
                              hipStream_t stream) {
  const float* x = (const float*)d_in[0];
  const float* p = (const float*)d_in[1];
  float* out = (float*)d_out;

  char* ws = (char*)d_ws;
  unsigned short* xb = (unsigned short*)ws;                       // 8 MB
  unsigned short* pb = (unsigned short*)(ws + (size_t)B_DIM * D_DIM * 2);  // 2 MB
  float* xsq = (float*)(ws + (size_t)(B_DIM + P_DIM) * D_DIM * 2);
  float* psq = xsq + B_DIM;

  prep_kernel<<<(B_DIM + P_DIM) / 4, 256, 0, stream>>>(x, p, xb, pb, xsq, psq);

  dist_gemm<<<(B_DIM / 128) * (P_DIM / 128), 256, 0, stream>>>(xb, pb, xsq, psq, out);
}